// Round 4
// baseline (210.061 us; speedup 1.0000x reference)
//
#include <hip/hip_runtime.h>

typedef float f32x4 __attribute__((ext_vector_type(4)));
typedef short s16x8 __attribute__((ext_vector_type(8)));
typedef short s16x4 __attribute__((ext_vector_type(4)));
typedef unsigned short ushort_t;

#define L_TOT 1360
#define BROWS 5440   // 4 * 1360
#define DM    1024
#define LDAS  40     // (fallback kernel only)

__device__ __forceinline__ float b2f(ushort_t u){
  union { unsigned int u; float f; } v; v.u = ((unsigned int)u) << 16; return v.f;
}
__device__ __forceinline__ ushort_t f2bf(float f){
  union { float f; unsigned int u; } v; v.f = f;
  unsigned int u = v.u;
  unsigned int r = u + 0x7fffu + ((u >> 16) & 1u);
  return (ushort_t)(r >> 16);
}
__device__ __forceinline__ unsigned cvtpk(float lo, float hi){
  unsigned r; asm("v_cvt_pk_bf16_f32 %0, %1, %2" : "=v"(r) : "v"(lo), "v"(hi)); return r;
}
__device__ __forceinline__ s16x4 mk4(unsigned a, unsigned b){
  union { unsigned w[2]; s16x4 v; } u; u.w[0] = a; u.w[1] = b; return u.v;
}
__device__ __forceinline__ int PL(int j){ return (j & 1) * 16 + (j >> 1) * 4; }
__device__ __forceinline__ int PH(int j){ return 8 + (j & 1) * 16 + (j >> 1) * 4; }

// async global->LDS, 16B per lane; LDS dest = wave-uniform base + lane*16
__device__ __forceinline__ void gload16(const ushort_t* g, ushort_t* l){
  __builtin_amdgcn_global_load_lds(
      (const __attribute__((address_space(1))) unsigned int*)g,
      (__attribute__((address_space(3))) unsigned int*)l, 16, 0, 0);
}

// fragment read from a linear [rows][32] bf16 tile with 16B-chunk XOR swizzle.
// source k-chunk16 G lives at LDS chunk C = G ^ (row & 3).
__device__ __forceinline__ s16x8 frag_read(const ushort_t* buf, int row, int lg){
  const int c16a = (lg >> 1) ^ (row & 3);
  const int c16b = c16a ^ 2;
  const int half = (lg & 1) * 4;
  s16x4 lo = *reinterpret_cast<const s16x4*>(&buf[row * 32 + c16a * 8 + half]);
  s16x4 hi = *reinterpret_cast<const s16x4*>(&buf[row * 32 + c16b * 8 + half]);
  s16x8 r;
  r[0]=lo[0]; r[1]=lo[1]; r[2]=lo[2]; r[3]=lo[3];
  r[4]=hi[0]; r[5]=hi[1]; r[6]=hi[2]; r[7]=hi[3];
  return r;
}

// ---------------------------------------------------------------- row stats (+ optional x->bf16)
__global__ __launch_bounds__(256) void stats_kernel(const float* __restrict__ x,
    float* __restrict__ mu, float* __restrict__ rs, ushort_t* __restrict__ xbf){
  const int row = blockIdx.x;
  const int t = threadIdx.x;
  f32x4 v = *reinterpret_cast<const f32x4*>(x + (size_t)row * DM + t * 4);
  if (xbf){
    uint2 o; o.x = cvtpk(v.x, v.y); o.y = cvtpk(v.z, v.w);
    *reinterpret_cast<uint2*>(xbf + (size_t)row * DM + t * 4) = o;
  }
  float s  = v.x + v.y + v.z + v.w;
  float s2 = v.x*v.x + v.y*v.y + v.z*v.z + v.w*v.w;
  #pragma unroll
  for (int off = 32; off; off >>= 1){ s += __shfl_xor(s, off); s2 += __shfl_xor(s2, off); }
  __shared__ float red[8];
  const int wid = t >> 6, lane = t & 63;
  if (lane == 0){ red[wid] = s; red[4 + wid] = s2; }
  __syncthreads();
  if (t == 0){
    s  = red[0] + red[1] + red[2] + red[3];
    s2 = red[4] + red[5] + red[6] + red[7];
    const float m = s * (1.0f / DM);
    const float var = s2 * (1.0f / DM) - m * m;
    mu[row] = m;
    rs[row] = rsqrtf(var + 1e-6f);
  }
}

// ---------------------------------------------------------------- cvec: cg = gamma^T Wq, cb = beta^T Wq
__global__ __launch_bounds__(256) void cvec_kernel(const float* __restrict__ Wq,
    const float* __restrict__ gamma, const float* __restrict__ beta,
    float* __restrict__ cg, float* __restrict__ cb){
  const int t = threadIdx.x;
  const int c = t & 15;
  const int kq = t >> 4;
  const int col = blockIdx.x * 16 + c;
  float sg = 0.f, sb = 0.f;
  for (int k = kq * 64; k < kq * 64 + 64; k++){
    const float w = Wq[(size_t)k * DM + col];
    sg += gamma[k] * w;
    sb += beta[k] * w;
  }
  __shared__ float shg[16][17], shb[16][17];
  shg[kq][c] = sg; shb[kq][c] = sb;
  __syncthreads();
  if (kq == 0){
    float tg = 0.f, tb = 0.f;
    #pragma unroll
    for (int q = 0; q < 16; q++){ tg += shg[q][c]; tb += shb[q][c]; }
    cg[col] = tg; cb[col] = tb;
  }
}

// ---------------------------------------------------------------- weight transpose
__global__ __launch_bounds__(256) void trans_kernel(
    const float* __restrict__ Wq, const float* __restrict__ Wk,
    const float* __restrict__ Wv, const float* __restrict__ Wfc,
    const float* __restrict__ gamma,
    ushort_t* __restrict__ Wqkv_t, ushort_t* __restrict__ Wfc_t){
  const int z = blockIdx.z;
  const float* W = (z == 0) ? Wq : (z == 1) ? Wk : (z == 2) ? Wv : Wfc;
  ushort_t* D = (z == 3) ? Wfc_t : (Wqkv_t + (size_t)z * DM * DM);
  __shared__ float sh[64][68];
  const int t = threadIdx.x;
  const int k0 = blockIdx.x * 64, n0 = blockIdx.y * 64;
  const int tr = t >> 4, tc = t & 15;
  #pragma unroll
  for (int it = 0; it < 4; it++){
    const int r = tr + it * 16;
    f32x4 v = *reinterpret_cast<const f32x4*>(W + (size_t)(k0 + r) * DM + n0 + tc * 4);
    if (z == 0){ const float g = gamma[k0 + r]; v.x *= g; v.y *= g; v.z *= g; v.w *= g; }
    *reinterpret_cast<f32x4*>(&sh[r][tc * 4]) = v;
  }
  __syncthreads();
  #pragma unroll
  for (int it = 0; it < 4; it++){
    const int rn = tr + it * 16;
    float a = sh[tc*4+0][rn], b = sh[tc*4+1][rn], c = sh[tc*4+2][rn], d = sh[tc*4+3][rn];
    uint2 w; w.x = cvtpk(a, b); w.y = cvtpk(c, d);
    *reinterpret_cast<uint2*>(D + (size_t)(n0 + rn) * DM + k0 + tc * 4) = w;
  }
}

// ---------------------------------------------------------------- fused QKV GEMM (fast path)
// A = x_bf [5440][1024] bf16, B = Wqkv_t [3072][1024] bf16. grid 1032 (XCD-chunked).
// BM=BN=128, BK=32, 4 waves 2x2. global_load_lds(16B) -> linear LDS, dbuf,
// 16B-chunk XOR source swizzle, one barrier per K-step (m97 structure).
__global__ __launch_bounds__(256) void qkv_gemm(const ushort_t* __restrict__ A,
    const ushort_t* __restrict__ Bt, ushort_t* __restrict__ Qb, ushort_t* __restrict__ KVb,
    const float* __restrict__ cg, const float* __restrict__ cb,
    const float* __restrict__ mu, const float* __restrict__ rs){
  __shared__ __align__(16) ushort_t As[2][128 * 32];
  __shared__ __align__(16) ushort_t Bs[2][128 * 32];
  const int tid = threadIdx.x;
  const int w = tid >> 6, lane = tid & 63;
  const int l15 = lane & 15, lg = lane >> 4;
  const int wr = w >> 1, wc = w & 1;

  const int bswz = (blockIdx.x & 7) * 129 + (blockIdx.x >> 3);   // 1032 = 8*129
  const int ty = bswz / 24, tx = bswz % 24;
  const int m0 = ty * 128;
  const int brow0 = tx * 128;

  // staging geometry: wave w covers rows [w*32, w*32+32), 2 calls x 16 rows
  const int srow = (lane >> 2);        // 0..15 within call
  const int c16 = lane & 3;
  int arow0 = m0 + w * 32 + srow;      int arow1 = arow0 + 16;
  if (arow0 > BROWS - 1) arow0 = BROWS - 1;
  if (arow1 > BROWS - 1) arow1 = BROWS - 1;
  const int lr0 = w * 32 + srow, lr1 = lr0 + 16;
  const int ga0 = c16 ^ (lr0 & 3), ga1 = c16 ^ (lr1 & 3);
  const ushort_t* a_src0 = A + (size_t)arow0 * DM + ga0 * 8;
  const ushort_t* a_src1 = A + (size_t)arow1 * DM + ga1 * 8;
  const ushort_t* b_src0 = Bt + (size_t)(brow0 + lr0) * DM + ga0 * 8;
  const ushort_t* b_src1 = Bt + (size_t)(brow0 + lr1) * DM + ga1 * 8;

  #define STAGE(P, K0) do { \
    gload16(a_src0 + (K0), &As[P][(w * 32) * 32]); \
    gload16(a_src1 + (K0), &As[P][(w * 32 + 16) * 32]); \
    gload16(b_src0 + (K0), &Bs[P][(w * 32) * 32]); \
    gload16(b_src1 + (K0), &Bs[P][(w * 32 + 16) * 32]); \
  } while(0)

  f32x4 acc[4][4];
  #pragma unroll
  for (int a = 0; a < 4; a++)
    #pragma unroll
    for (int b = 0; b < 4; b++) acc[a][b] = (f32x4){0.f,0.f,0.f,0.f};

  STAGE(0, 0);
  __syncthreads();

  for (int kt = 0; kt < 32; ++kt){
    const int p = kt & 1;
    if (kt < 31) STAGE(p ^ 1, (kt + 1) * 32);

    s16x8 af[4], bf[4];
    #pragma unroll
    for (int mi = 0; mi < 4; mi++)
      af[mi] = frag_read(As[p], wr*64 + mi*16 + l15, lg);
    #pragma unroll
    for (int ni = 0; ni < 4; ni++)
      bf[ni] = frag_read(Bs[p], wc*64 + ni*16 + l15, lg);
    #pragma unroll
    for (int mi = 0; mi < 4; mi++)
      #pragma unroll
      for (int ni = 0; ni < 4; ni++)
        acc[mi][ni] = __builtin_amdgcn_mfma_f32_16x16x32_bf16(af[mi], bf[ni], acc[mi][ni], 0, 0, 0);

    __syncthreads();
  }
  #undef STAGE

  const bool isQ = (tx < 8);
  ushort_t* outp; int ostride, col0;
  if (tx < 8)      { outp = Qb;  ostride = 1024; col0 = tx * 128; }
  else if (tx < 16){ outp = KVb; ostride = 2048; col0 = (tx - 8) * 128; }
  else             { outp = KVb; ostride = 2048; col0 = 1024 + (tx - 16) * 128; }

  #pragma unroll
  for (int mi = 0; mi < 4; mi++){
    #pragma unroll
    for (int r = 0; r < 4; r++){
      const int gm = m0 + wr*64 + mi*16 + lg*4 + r;
      if (gm < BROWS){
        const float rsv = isQ ? rs[gm] : 0.f;
        const float muv = isQ ? mu[gm] : 0.f;
        #pragma unroll
        for (int ni = 0; ni < 4; ni++){
          const int nl = wc*64 + ni*16 + l15;
          float v = acc[mi][ni][r];
          if (isQ) v = 0.125f * (rsv * (v - muv * cg[brow0 + nl]) + cb[brow0 + nl]);
          outp[(size_t)gm * ostride + col0 + nl] = f2bf(v);
        }
      }
    }
  }
}

// ---------------------------------------------------------------- fused QKV GEMM (fallback, f32 A, r3-proven)
__global__ __launch_bounds__(256) void qkv_gemm_f32(const float* __restrict__ A,
    const ushort_t* __restrict__ Bt, ushort_t* __restrict__ Qb, ushort_t* __restrict__ KVb,
    const float* __restrict__ cg, const float* __restrict__ cb,
    const float* __restrict__ mu, const float* __restrict__ rs){
  __shared__ __align__(16) ushort_t As[2][128 * LDAS];
  __shared__ __align__(16) ushort_t Bs[2][128 * LDAS];
  const int tid = threadIdx.x;
  const int wid = tid >> 6, lane = tid & 63;
  const int l15 = lane & 15, lg = lane >> 4;
  const int wr = wid >> 1, wc = wid & 1;
  const int flat = blockIdx.x;
  const int ty = flat / 24, tx = flat % 24;
  const int m0 = ty * 128;
  const int brow0 = tx * 128;

  const int sr  = tid >> 1;
  const int j0  = (tid & 1) * 2, j1 = j0 + 1;
  int garow = m0 + sr; if (garow > BROWS - 1) garow = BROWS - 1;
  const float*    ap = A  + (size_t)garow * DM;
  const ushort_t* bp = Bt + (size_t)(brow0 + sr) * DM;

  f32x4 ra0, ra1, ra2, ra3; s16x8 rb0, rb1;
  #define QLOAD(K0) do { \
    ra0 = *reinterpret_cast<const f32x4*>(ap + (K0) + j0 * 8); \
    ra1 = *reinterpret_cast<const f32x4*>(ap + (K0) + j0 * 8 + 4); \
    ra2 = *reinterpret_cast<const f32x4*>(ap + (K0) + j1 * 8); \
    ra3 = *reinterpret_cast<const f32x4*>(ap + (K0) + j1 * 8 + 4); \
    rb0 = *reinterpret_cast<const s16x8*>(bp + (K0) + j0 * 8); \
    rb1 = *reinterpret_cast<const s16x8*>(bp + (K0) + j1 * 8); \
  } while(0)
  #define QWRITE(P) do { \
    *reinterpret_cast<s16x4*>(&As[P][sr * LDAS + PL(j0)]) = mk4(cvtpk(ra0.x, ra0.y), cvtpk(ra0.z, ra0.w)); \
    *reinterpret_cast<s16x4*>(&As[P][sr * LDAS + PH(j0)]) = mk4(cvtpk(ra1.x, ra1.y), cvtpk(ra1.z, ra1.w)); \
    *reinterpret_cast<s16x4*>(&As[P][sr * LDAS + PL(j1)]) = mk4(cvtpk(ra2.x, ra2.y), cvtpk(ra2.z, ra2.w)); \
    *reinterpret_cast<s16x4*>(&As[P][sr * LDAS + PH(j1)]) = mk4(cvtpk(ra3.x, ra3.y), cvtpk(ra3.z, ra3.w)); \
    s16x4 b0l, b0h, b1l, b1h; \
    b0l[0]=rb0[0]; b0l[1]=rb0[1]; b0l[2]=rb0[2]; b0l[3]=rb0[3]; \
    b0h[0]=rb0[4]; b0h[1]=rb0[5]; b0h[2]=rb0[6]; b0h[3]=rb0[7]; \
    b1l[0]=rb1[0]; b1l[1]=rb1[1]; b1l[2]=rb1[2]; b1l[3]=rb1[3]; \
    b1h[0]=rb1[4]; b1h[1]=rb1[5]; b1h[2]=rb1[6]; b1h[3]=rb1[7]; \
    *reinterpret_cast<s16x4*>(&Bs[P][sr * LDAS + PL(j0)]) = b0l; \
    *reinterpret_cast<s16x4*>(&Bs[P][sr * LDAS + PH(j0)]) = b0h; \
    *reinterpret_cast<s16x4*>(&Bs[P][sr * LDAS + PL(j1)]) = b1l; \
    *reinterpret_cast<s16x4*>(&Bs[P][sr * LDAS + PH(j1)]) = b1h; \
  } while(0)

  f32x4 acc[4][4];
  #pragma unroll
  for (int a = 0; a < 4; a++)
    #pragma unroll
    for (int b = 0; b < 4; b++) acc[a][b] = (f32x4){0.f,0.f,0.f,0.f};

  QLOAD(0);
  QWRITE(0);
  __syncthreads();

  for (int kt = 0; kt < 32; ++kt){
    const int p = kt & 1;
    if (kt < 31) QLOAD((kt + 1) * 32);

    s16x8 af[4], bf[4];
    #pragma unroll
    for (int mi = 0; mi < 4; mi++)
      af[mi] = *reinterpret_cast<const s16x8*>(&As[p][(wr*64 + mi*16 + l15) * LDAS + lg * 8]);
    #pragma unroll
    for (int ni = 0; ni < 4; ni++)
      bf[ni] = *reinterpret_cast<const s16x8*>(&Bs[p][(wc*64 + ni*16 + l15) * LDAS + lg * 8]);
    #pragma unroll
    for (int mi = 0; mi < 4; mi++)
      #pragma unroll
      for (int ni = 0; ni < 4; ni++)
        acc[mi][ni] = __builtin_amdgcn_mfma_f32_16x16x32_bf16(af[mi], bf[ni], acc[mi][ni], 0, 0, 0);

    if (kt < 31){
      QWRITE(p ^ 1);
      __syncthreads();
    }
  }
  #undef QLOAD
  #undef QWRITE

  const bool isQ = (tx < 8);
  ushort_t* outp; int ostride, col0;
  if (tx < 8)      { outp = Qb;  ostride = 1024; col0 = tx * 128; }
  else if (tx < 16){ outp = KVb; ostride = 2048; col0 = (tx - 8) * 128; }
  else             { outp = KVb; ostride = 2048; col0 = 1024 + (tx - 16) * 128; }

  #pragma unroll
  for (int mi = 0; mi < 4; mi++){
    #pragma unroll
    for (int r = 0; r < 4; r++){
      const int gm = m0 + wr*64 + mi*16 + lg*4 + r;
      if (gm < BROWS){
        const float rsv = isQ ? rs[gm] : 0.f;
        const float muv = isQ ? mu[gm] : 0.f;
        #pragma unroll
        for (int ni = 0; ni < 4; ni++){
          const int nl = wc*64 + ni*16 + l15;
          float v = acc[mi][ni][r];
          if (isQ) v = 0.125f * (rsv * (v - muv * cg[brow0 + nl]) + cb[brow0 + nl]);
          outp[(size_t)gm * ostride + col0 + nl] = f2bf(v);
        }
      }
    }
  }
}

// ---------------------------------------------------------------- FC GEMM
// out = ctx @ Wfc + bias + resid.  BM=64, BN=128, grid 680 = 8 XCD chunks x 85.
__global__ __launch_bounds__(256) void fc_gemm(const ushort_t* __restrict__ A,
    const ushort_t* __restrict__ Bt, const float* __restrict__ bias,
    const float* __restrict__ resid, float* __restrict__ out){
  __shared__ __align__(16) ushort_t As[2][64 * 32];
  __shared__ __align__(16) ushort_t Bs[2][128 * 32];
  const int tid = threadIdx.x;
  const int w = tid >> 6, lane = tid & 63;
  const int l15 = lane & 15, lg = lane >> 4;
  const int wr = w >> 1, wc = w & 1;

  const int bswz = (blockIdx.x & 7) * 85 + (blockIdx.x >> 3);    // 680 = 8*85
  const int ty = bswz >> 3, tx = bswz & 7;
  const int m0 = ty * 64, n0 = tx * 128;

  const int srow = (lane >> 2);
  const int c16 = lane & 3;
  const int lra = w * 16 + srow;                    // A rows: wave w covers 16
  const int lrb0 = w * 32 + srow, lrb1 = lrb0 + 16; // B rows: wave w covers 32
  const int gaa = c16 ^ (lra & 3);
  const int gb0 = c16 ^ (lrb0 & 3), gb1 = c16 ^ (lrb1 & 3);
  const ushort_t* a_src  = A + (size_t)(m0 + lra) * DM + gaa * 8;
  const ushort_t* b_src0 = Bt + (size_t)(n0 + lrb0) * DM + gb0 * 8;
  const ushort_t* b_src1 = Bt + (size_t)(n0 + lrb1) * DM + gb1 * 8;

  #define FSTAGE(P, K0) do { \
    gload16(a_src + (K0), &As[P][(w * 16) * 32]); \
    gload16(b_src0 + (K0), &Bs[P][(w * 32) * 32]); \
    gload16(b_src1 + (K0), &Bs[P][(w * 32 + 16) * 32]); \
  } while(0)

  f32x4 acc[2][4];
  #pragma unroll
  for (int a = 0; a < 2; a++)
    #pragma unroll
    for (int b = 0; b < 4; b++) acc[a][b] = (f32x4){0.f,0.f,0.f,0.f};

  FSTAGE(0, 0);
  __syncthreads();

  for (int kt = 0; kt < 32; ++kt){
    const int p = kt & 1;
    if (kt < 31) FSTAGE(p ^ 1, (kt + 1) * 32);

    s16x8 af[2], bf[4];
    #pragma unroll
    for (int mi = 0; mi < 2; mi++)
      af[mi] = frag_read(As[p], wr*32 + mi*16 + l15, lg);
    #pragma unroll
    for (int ni = 0; ni < 4; ni++)
      bf[ni] = frag_read(Bs[p], wc*64 + ni*16 + l15, lg);
    #pragma unroll
    for (int mi = 0; mi < 2; mi++)
      #pragma unroll
      for (int ni = 0; ni < 4; ni++)
        acc[mi][ni] = __builtin_amdgcn_mfma_f32_16x16x32_bf16(af[mi], bf[ni], acc[mi][ni], 0, 0, 0);

    __syncthreads();
  }
  #undef FSTAGE

  #pragma unroll
  for (int mi = 0; mi < 2; mi++)
    #pragma unroll
    for (int ni = 0; ni < 4; ni++){
      const int gn = n0 + wc*64 + ni*16 + l15;
      #pragma unroll
      for (int r = 0; r < 4; r++){
        const int gm = m0 + wr*32 + mi*16 + lg*4 + r;
        out[(size_t)gm * DM + gn] = acc[mi][ni][r] + bias[gn] + resid[(size_t)gm * DM + gn];
      }
    }
}

// ---------------------------------------------------------------- sparse PAM attention
__global__ __launch_bounds__(256) void attn_kernel(const ushort_t* __restrict__ Q,
    const ushort_t* __restrict__ KV, ushort_t* __restrict__ ctx){
  const int wid = threadIdx.x >> 6, lane = threadIdx.x & 63;
  const int gw = blockIdx.x * 4 + wid;
  const int b = gw / L_TOT;
  const int rem = gw - b * L_TOT;
  const int h = rem / 85;
  const int qt = rem - h * 85;
  const int l15 = lane & 15, g = lane >> 4;
  const int i = qt * 16 + l15;
  const int row = b * L_TOT + i;
  const int brow0 = b * L_TOT;

  int st, sz;
  if      (i < 1024){ st = 0;    sz = 1024; }
  else if (i < 1280){ st = 1024; sz = 256;  }
  else if (i < 1344){ st = 1280; sz = 64;   }
  else              { st = 1344; sz = 16;   }

  int key[10]; bool val[10];
  #pragma unroll
  for (int s = 0; s < 5; s++){
    int j = i - 2 + s;
    val[s] = (j >= st) && (j < st + sz);
    key[s] = val[s] ? j : i;
  }
  const bool haskid = (i >= 1024);
  const int cs = haskid ? (st - sz * 4 + (i - st) * 4) : i;
  #pragma unroll
  for (int c = 0; c < 4; c++){ key[5 + c] = haskid ? (cs + c) : i; val[5 + c] = haskid; }
  const bool haspar = (i < 1344);
  key[9] = haspar ? (st + sz + ((i - st) >> 2)) : i;
  val[9] = haspar;

  const int dcol = h * 64 + g * 16;
  const ushort_t* qp = Q + (size_t)row * DM + dcol;
  s16x8 q0 = *reinterpret_cast<const s16x8*>(qp);
  s16x8 q1 = *reinterpret_cast<const s16x8*>(qp + 8);
  float qf[16];
  #pragma unroll
  for (int j = 0; j < 8; j++){ qf[j] = b2f((ushort_t)q0[j]); qf[8 + j] = b2f((ushort_t)q1[j]); }

  size_t koff[10];
  float sc[10];
  #pragma unroll
  for (int s = 0; s < 10; s++){
    koff[s] = (size_t)(brow0 + key[s]) * 2048 + dcol;
    const ushort_t* kp = KV + koff[s];
    s16x8 k0 = *reinterpret_cast<const s16x8*>(kp);
    s16x8 k1 = *reinterpret_cast<const s16x8*>(kp + 8);
    float p = 0.f;
    #pragma unroll
    for (int j = 0; j < 8; j++){
      p += qf[j]     * b2f((ushort_t)k0[j]);
      p += qf[8 + j] * b2f((ushort_t)k1[j]);
    }
    p += __shfl_xor(p, 16);
    p += __shfl_xor(p, 32);
    sc[s] = val[s] ? p : -1e30f;
  }

  float m = sc[0];
  #pragma unroll
  for (int s = 1; s < 10; s++) m = fmaxf(m, sc[s]);
  float e[10]; float sum = 0.f;
  #pragma unroll
  for (int s = 0; s < 10; s++){ e[s] = __expf(sc[s] - m); sum += e[s]; }
  const float inv = 1.0f / sum;

  float accv[16];
  #pragma unroll
  for (int j = 0; j < 16; j++) accv[j] = 0.f;
  #pragma unroll
  for (int s = 0; s < 10; s++){
    const ushort_t* vp = KV + koff[s] + 1024;
    s16x8 v0 = *reinterpret_cast<const s16x8*>(vp);
    s16x8 v1 = *reinterpret_cast<const s16x8*>(vp + 8);
    const float w = e[s];
    #pragma unroll
    for (int j = 0; j < 8; j++){
      accv[j]     += w * b2f((ushort_t)v0[j]);
      accv[8 + j] += w * b2f((ushort_t)v1[j]);
    }
  }

  uint4 o0, o1;
  o0.x = cvtpk(accv[0]*inv,  accv[1]*inv);  o0.y = cvtpk(accv[2]*inv,  accv[3]*inv);
  o0.z = cvtpk(accv[4]*inv,  accv[5]*inv);  o0.w = cvtpk(accv[6]*inv,  accv[7]*inv);
  o1.x = cvtpk(accv[8]*inv,  accv[9]*inv);  o1.y = cvtpk(accv[10]*inv, accv[11]*inv);
  o1.z = cvtpk(accv[12]*inv, accv[13]*inv); o1.w = cvtpk(accv[14]*inv, accv[15]*inv);
  ushort_t* op = ctx + (size_t)row * DM + dcol;
  *reinterpret_cast<uint4*>(op) = o0;
  *reinterpret_cast<uint4*>(op + 8) = o1;
}

// ---------------------------------------------------------------- launch
extern "C" void kernel_launch(void* const* d_in, const int* in_sizes, int n_in,
                              void* d_out, int out_size, void* d_ws, size_t ws_size,
                              hipStream_t stream){
  (void)in_sizes; (void)n_in; (void)out_size;
  const float* x     = (const float*)d_in[0];
  const float* Wq    = (const float*)d_in[1];
  const float* Wk    = (const float*)d_in[2];
  const float* Wv    = (const float*)d_in[3];
  const float* Wfc   = (const float*)d_in[4];
  const float* bfc   = (const float*)d_in[5];
  const float* gamma = (const float*)d_in[6];
  const float* beta  = (const float*)d_in[7];
  float* out = (float*)d_out;

  char* ws = (char*)d_ws;
  const size_t SLAB = (size_t)BROWS * DM * sizeof(ushort_t);   // 11,141,120 B
  // C [0, SLAB): weights + vectors
  ushort_t* Wqkv_t = (ushort_t*)(ws);                           // 6 MB
  ushort_t* Wfc_t  = (ushort_t*)(ws + 6291456);                 // 2 MB
  float*    cg     = (float*)(ws + 8388608);
  float*    cb     = (float*)(ws + 8392704);
  float*    muv    = (float*)(ws + 8396800);
  float*    rsv    = (float*)(ws + 8418560);
  // D [SLAB, 2*SLAB): Q -> ctx (in place)
  ushort_t* Qb  = (ushort_t*)(ws + SLAB);
  ushort_t* ctx = Qb;
  // E [2*SLAB, 4*SLAB): KV interleaved [row][K|V] stride 2048
  ushort_t* KVb = (ushort_t*)(ws + 2 * SLAB);
  // G [4*SLAB, 5*SLAB): x as bf16 (fast path only)
  const bool fast = ws_size >= 5 * SLAB;
  ushort_t* x_bf = fast ? (ushort_t*)(ws + 4 * SLAB) : nullptr;

  stats_kernel<<<BROWS, 256, 0, stream>>>(x, muv, rsv, x_bf);
  cvec_kernel<<<64, 256, 0, stream>>>(Wq, gamma, beta, cg, cb);
  trans_kernel<<<dim3(16, 16, 4), 256, 0, stream>>>(Wq, Wk, Wv, Wfc, gamma, Wqkv_t, Wfc_t);
  if (fast)
    qkv_gemm<<<1032, 256, 0, stream>>>(x_bf, Wqkv_t, Qb, KVb, cg, cb, muv, rsv);
  else
    qkv_gemm_f32<<<1032, 256, 0, stream>>>(x, Wqkv_t, Qb, KVb, cg, cb, muv, rsv);
  attn_kernel<<<L_TOT, 256, 0, stream>>>(Qb, KVb, ctx);
  fc_gemm<<<680, 256, 0, stream>>>(ctx, Wfc_t, bfc, x, out);
}

// Round 5
// 150.197 us; speedup vs baseline: 1.3986x; 1.3986x over previous
//
#include <hip/hip_runtime.h>

typedef float f32x4 __attribute__((ext_vector_type(4)));
typedef short s16x8 __attribute__((ext_vector_type(8)));
typedef unsigned short ushort_t;

#define L_TOT 1360
#define BROWS 5440   // 4 * 1360
#define DM    1024

__device__ __forceinline__ float b2f(ushort_t u){
  union { unsigned int u; float f; } v; v.u = ((unsigned int)u) << 16; return v.f;
}
__device__ __forceinline__ ushort_t f2bf(float f){
  union { float f; unsigned int u; } v; v.f = f;
  unsigned int u = v.u;
  unsigned int r = u + 0x7fffu + ((u >> 16) & 1u);
  return (ushort_t)(r >> 16);
}
__device__ __forceinline__ unsigned cvtpk(float lo, float hi){
  unsigned r; asm("v_cvt_pk_bf16_f32 %0, %1, %2" : "=v"(r) : "v"(lo), "v"(hi)); return r;
}

// async global->LDS, 16B per lane; LDS dest = wave-uniform base + lane*16
__device__ __forceinline__ void gload16(const ushort_t* g, ushort_t* l){
  __builtin_amdgcn_global_load_lds(
      (const __attribute__((address_space(1))) unsigned int*)g,
      (__attribute__((address_space(3))) unsigned int*)l, 16, 0, 0);
}

// ---------------------------------------------------------------------------
// sigma k-layout: within each 32-k block, quads stored as [q0 q4 q1 q5 q2 q6 q3 q7]
// (stored chunk c = 16B = MFMA fragment k-set {4c+i} u {16+4c+i}).
// Global quad J (k = 4J..4J+3): block = J>>3, j = J&7,
//   stored short offset = 32*(J>>3) + 8*(j&3) + 4*(j>>2).
// LDS bank swizzle (involution): slot s of row r holds stored-chunk s ^ ((r>>1)&3).
// ---------------------------------------------------------------------------

// ---------------------------------------------------------------- row stats + x -> bf16 (sigma)
__global__ __launch_bounds__(256) void stats_kernel(const float* __restrict__ x,
    float* __restrict__ mu, float* __restrict__ rs, ushort_t* __restrict__ xbf){
  const int row = blockIdx.x;
  const int t = threadIdx.x;
  f32x4 v = *reinterpret_cast<const f32x4*>(x + (size_t)row * DM + t * 4);
  {
    const int off = 32 * (t >> 3) + 8 * (t & 3) + 4 * ((t >> 2) & 1);
    uint2 o; o.x = cvtpk(v.x, v.y); o.y = cvtpk(v.z, v.w);
    *reinterpret_cast<uint2*>(xbf + (size_t)row * DM + off) = o;
  }
  float s  = v.x + v.y + v.z + v.w;
  float s2 = v.x*v.x + v.y*v.y + v.z*v.z + v.w*v.w;
  #pragma unroll
  for (int off = 32; off; off >>= 1){ s += __shfl_xor(s, off); s2 += __shfl_xor(s2, off); }
  __shared__ float red[8];
  const int wid = t >> 6, lane = t & 63;
  if (lane == 0){ red[wid] = s; red[4 + wid] = s2; }
  __syncthreads();
  if (t == 0){
    s  = red[0] + red[1] + red[2] + red[3];
    s2 = red[4] + red[5] + red[6] + red[7];
    const float m = s * (1.0f / DM);
    const float var = s2 * (1.0f / DM) - m * m;
    mu[row] = m;
    rs[row] = rsqrtf(var + 1e-6f);
  }
}

// ---------------------------------------------------------------- cvec: cg = gamma^T Wq, cb = beta^T Wq
__global__ __launch_bounds__(256) void cvec_kernel(const float* __restrict__ Wq,
    const float* __restrict__ gamma, const float* __restrict__ beta,
    float* __restrict__ cg, float* __restrict__ cb){
  const int t = threadIdx.x;
  const int c = t & 15;
  const int kq = t >> 4;
  const int col = blockIdx.x * 16 + c;
  float sg = 0.f, sb = 0.f;
  for (int k = kq * 64; k < kq * 64 + 64; k++){
    const float w = Wq[(size_t)k * DM + col];
    sg += gamma[k] * w;
    sb += beta[k] * w;
  }
  __shared__ float shg[16][17], shb[16][17];
  shg[kq][c] = sg; shb[kq][c] = sb;
  __syncthreads();
  if (kq == 0){
    float tg = 0.f, tb = 0.f;
    #pragma unroll
    for (int q = 0; q < 16; q++){ tg += shg[q][c]; tb += shb[q][c]; }
    cg[col] = tg; cb[col] = tb;
  }
}

// ---------------------------------------------------------------- weight transpose (sigma k-layout out)
__global__ __launch_bounds__(256) void trans_kernel(
    const float* __restrict__ Wq, const float* __restrict__ Wk,
    const float* __restrict__ Wv, const float* __restrict__ Wfc,
    const float* __restrict__ gamma,
    ushort_t* __restrict__ Wqkv_t, ushort_t* __restrict__ Wfc_t){
  const int z = blockIdx.z;
  const float* W = (z == 0) ? Wq : (z == 1) ? Wk : (z == 2) ? Wv : Wfc;
  ushort_t* D = (z == 3) ? Wfc_t : (Wqkv_t + (size_t)z * DM * DM);
  __shared__ float sh[64][68];
  const int t = threadIdx.x;
  const int k0 = blockIdx.x * 64, n0 = blockIdx.y * 64;
  const int tr = t >> 4, tc = t & 15;
  #pragma unroll
  for (int it = 0; it < 4; it++){
    const int r = tr + it * 16;
    f32x4 v = *reinterpret_cast<const f32x4*>(W + (size_t)(k0 + r) * DM + n0 + tc * 4);
    if (z == 0){ const float g = gamma[k0 + r]; v.x *= g; v.y *= g; v.z *= g; v.w *= g; }
    *reinterpret_cast<f32x4*>(&sh[r][tc * 4]) = v;
  }
  __syncthreads();
  // quad written: global k = k0 + 4*tc .. +3  ->  sigma offset
  const int soff = k0 + 32 * (tc >> 3) + 8 * (tc & 3) + 4 * ((tc >> 2) & 1);
  #pragma unroll
  for (int it = 0; it < 4; it++){
    const int rn = tr + it * 16;
    float a = sh[tc*4+0][rn], b = sh[tc*4+1][rn], c = sh[tc*4+2][rn], d = sh[tc*4+3][rn];
    uint2 w; w.x = cvtpk(a, b); w.y = cvtpk(c, d);
    *reinterpret_cast<uint2*>(D + (size_t)(n0 + rn) * DM + soff) = w;
  }
}

// ---------------------------------------------------------------- fused QKV GEMM
// A = x_bf (sigma), B = Wqkv_t (sigma). BM=BN=128, BK=32, 4 waves 2x2.
// global_load_lds(16B) -> LDS with slot-XOR bank swizzle; frag = 1 ds_read_b128.
__global__ __launch_bounds__(256) void qkv_gemm(const ushort_t* __restrict__ A,
    const ushort_t* __restrict__ Bt, ushort_t* __restrict__ Qb, ushort_t* __restrict__ KVb,
    const float* __restrict__ cg, const float* __restrict__ cb,
    const float* __restrict__ mu, const float* __restrict__ rs){
  __shared__ __align__(16) ushort_t As[2][128 * 32];
  __shared__ __align__(16) ushort_t Bs[2][128 * 32];
  const int tid = threadIdx.x;
  const int w = tid >> 6, lane = tid & 63;
  const int l15 = lane & 15, lg = lane >> 4;
  const int wr = w >> 1, wc = w & 1;

  const int bswz = (blockIdx.x & 7) * 129 + (blockIdx.x >> 3);   // 1032 = 8*129, bijective
  const int ty = bswz / 24, tx = bswz % 24;
  const int m0 = ty * 128, brow0 = tx * 128;

  // staging: lane = (row-in-16, slot); source chunk = slot ^ ((r>>1)&3)
  const int rch = lane >> 2, slot = lane & 3;
  const int gch = slot ^ ((rch >> 1) & 3);
  int ar0 = m0 + w * 32 + rch;      if (ar0 > BROWS - 1) ar0 = BROWS - 1;
  int ar1 = m0 + w * 32 + 16 + rch; if (ar1 > BROWS - 1) ar1 = BROWS - 1;
  const ushort_t* a_src0 = A  + (size_t)ar0 * DM + gch * 8;
  const ushort_t* a_src1 = A  + (size_t)ar1 * DM + gch * 8;
  const ushort_t* b_src0 = Bt + (size_t)(brow0 + w * 32      + rch) * DM + gch * 8;
  const ushort_t* b_src1 = Bt + (size_t)(brow0 + w * 32 + 16 + rch) * DM + gch * 8;

  #define STAGE(P, K0) do { \
    gload16(a_src0 + (K0), &As[P][(w * 32     ) * 32]); \
    gload16(a_src1 + (K0), &As[P][(w * 32 + 16) * 32]); \
    gload16(b_src0 + (K0), &Bs[P][(w * 32     ) * 32]); \
    gload16(b_src1 + (K0), &Bs[P][(w * 32 + 16) * 32]); \
  } while(0)

  const int fs = lg ^ ((l15 >> 1) & 3);   // read slot (same involution)

  f32x4 acc[4][4];
  #pragma unroll
  for (int a = 0; a < 4; a++)
    #pragma unroll
    for (int b = 0; b < 4; b++) acc[a][b] = (f32x4){0.f,0.f,0.f,0.f};

  STAGE(0, 0);
  __syncthreads();

  for (int kt = 0; kt < 32; ++kt){
    const int p = kt & 1;
    if (kt < 31) STAGE(p ^ 1, (kt + 1) * 32);

    s16x8 af[4], bf[4];
    #pragma unroll
    for (int mi = 0; mi < 4; mi++)
      af[mi] = *reinterpret_cast<const s16x8*>(&As[p][(wr*64 + mi*16 + l15) * 32 + fs * 8]);
    #pragma unroll
    for (int ni = 0; ni < 4; ni++)
      bf[ni] = *reinterpret_cast<const s16x8*>(&Bs[p][(wc*64 + ni*16 + l15) * 32 + fs * 8]);
    #pragma unroll
    for (int mi = 0; mi < 4; mi++)
      #pragma unroll
      for (int ni = 0; ni < 4; ni++)
        acc[mi][ni] = __builtin_amdgcn_mfma_f32_16x16x32_bf16(af[mi], bf[ni], acc[mi][ni], 0, 0, 0);

    __syncthreads();
  }
  #undef STAGE

  const bool isQ = (tx < 8);
  ushort_t* outp; int ostride, col0;
  if (tx < 8)      { outp = Qb;  ostride = 1024; col0 = tx * 128; }
  else if (tx < 16){ outp = KVb; ostride = 2048; col0 = (tx - 8) * 128; }
  else             { outp = KVb; ostride = 2048; col0 = 1024 + (tx - 16) * 128; }

  #pragma unroll
  for (int mi = 0; mi < 4; mi++){
    #pragma unroll
    for (int r = 0; r < 4; r++){
      const int gm = m0 + wr*64 + mi*16 + lg*4 + r;
      if (gm < BROWS){
        const float rsv = isQ ? rs[gm] : 0.f;
        const float muv = isQ ? mu[gm] : 0.f;
        #pragma unroll
        for (int ni = 0; ni < 4; ni++){
          const int nl = wc*64 + ni*16 + l15;
          float v = acc[mi][ni][r];
          if (isQ) v = 0.125f * (rsv * (v - muv * cg[brow0 + nl]) + cb[brow0 + nl]);
          outp[(size_t)gm * ostride + col0 + nl] = f2bf(v);
        }
      }
    }
  }
}

// ---------------------------------------------------------------- FC GEMM
// out = ctx @ Wfc + bias + resid.  BM=64, BN=128, grid 680 = 8 XCD chunks x 85.
__global__ __launch_bounds__(256) void fc_gemm(const ushort_t* __restrict__ A,
    const ushort_t* __restrict__ Bt, const float* __restrict__ bias,
    const float* __restrict__ resid, float* __restrict__ out){
  __shared__ __align__(16) ushort_t As[2][64 * 32];
  __shared__ __align__(16) ushort_t Bs[2][128 * 32];
  const int tid = threadIdx.x;
  const int w = tid >> 6, lane = tid & 63;
  const int l15 = lane & 15, lg = lane >> 4;
  const int wr = w >> 1, wc = w & 1;

  const int bswz = (blockIdx.x & 7) * 85 + (blockIdx.x >> 3);    // 680 = 8*85, bijective
  const int ty = bswz >> 3, tx = bswz & 7;
  const int m0 = ty * 64, n0 = tx * 128;

  const int rch = lane >> 2, slot = lane & 3;
  const int gch = slot ^ ((rch >> 1) & 3);
  const ushort_t* a_src  = A  + (size_t)(m0 + w * 16 + rch) * DM + gch * 8;
  const ushort_t* b_src0 = Bt + (size_t)(n0 + w * 32      + rch) * DM + gch * 8;
  const ushort_t* b_src1 = Bt + (size_t)(n0 + w * 32 + 16 + rch) * DM + gch * 8;

  #define FSTAGE(P, K0) do { \
    gload16(a_src  + (K0), &As[P][(w * 16     ) * 32]); \
    gload16(b_src0 + (K0), &Bs[P][(w * 32     ) * 32]); \
    gload16(b_src1 + (K0), &Bs[P][(w * 32 + 16) * 32]); \
  } while(0)

  const int fs = lg ^ ((l15 >> 1) & 3);

  f32x4 acc[2][4];
  #pragma unroll
  for (int a = 0; a < 2; a++)
    #pragma unroll
    for (int b = 0; b < 4; b++) acc[a][b] = (f32x4){0.f,0.f,0.f,0.f};

  FSTAGE(0, 0);
  __syncthreads();

  for (int kt = 0; kt < 32; ++kt){
    const int p = kt & 1;
    if (kt < 31) FSTAGE(p ^ 1, (kt + 1) * 32);

    s16x8 af[2], bf[4];
    #pragma unroll
    for (int mi = 0; mi < 2; mi++)
      af[mi] = *reinterpret_cast<const s16x8*>(&As[p][(wr*32 + mi*16 + l15) * 32 + fs * 8]);
    #pragma unroll
    for (int ni = 0; ni < 4; ni++)
      bf[ni] = *reinterpret_cast<const s16x8*>(&Bs[p][(wc*64 + ni*16 + l15) * 32 + fs * 8]);
    #pragma unroll
    for (int mi = 0; mi < 2; mi++)
      #pragma unroll
      for (int ni = 0; ni < 4; ni++)
        acc[mi][ni] = __builtin_amdgcn_mfma_f32_16x16x32_bf16(af[mi], bf[ni], acc[mi][ni], 0, 0, 0);

    __syncthreads();
  }
  #undef FSTAGE

  #pragma unroll
  for (int mi = 0; mi < 2; mi++)
    #pragma unroll
    for (int ni = 0; ni < 4; ni++){
      const int gn = n0 + wc*64 + ni*16 + l15;
      #pragma unroll
      for (int r = 0; r < 4; r++){
        const int gm = m0 + wr*32 + mi*16 + lg*4 + r;
        out[(size_t)gm * DM + gn] = acc[mi][ni][r] + bias[gn] + resid[(size_t)gm * DM + gn];
      }
    }
}

// ---------------------------------------------------------------- sparse PAM attention
// Wave = 16 queries x 4 d-groups. ctx written IN-PLACE over Q, in sigma k-layout
// (4 x uint2 stores) so it can feed fc_gemm's staging directly.
__global__ __launch_bounds__(256) void attn_kernel(const ushort_t* __restrict__ Q,
    const ushort_t* __restrict__ KV, ushort_t* __restrict__ ctx){
  const int wid = threadIdx.x >> 6, lane = threadIdx.x & 63;
  const int gw = blockIdx.x * 4 + wid;
  const int b = gw / L_TOT;
  const int rem = gw - b * L_TOT;
  const int h = rem / 85;
  const int qt = rem - h * 85;
  const int l15 = lane & 15, g = lane >> 4;
  const int i = qt * 16 + l15;
  const int row = b * L_TOT + i;
  const int brow0 = b * L_TOT;

  int st, sz;
  if      (i < 1024){ st = 0;    sz = 1024; }
  else if (i < 1280){ st = 1024; sz = 256;  }
  else if (i < 1344){ st = 1280; sz = 64;   }
  else              { st = 1344; sz = 16;   }

  int key[10]; bool val[10];
  #pragma unroll
  for (int s = 0; s < 5; s++){
    int j = i - 2 + s;
    val[s] = (j >= st) && (j < st + sz);
    key[s] = val[s] ? j : i;
  }
  const bool haskid = (i >= 1024);
  const int cs = haskid ? (st - sz * 4 + (i - st) * 4) : i;
  #pragma unroll
  for (int c = 0; c < 4; c++){ key[5 + c] = haskid ? (cs + c) : i; val[5 + c] = haskid; }
  const bool haspar = (i < 1344);
  key[9] = haspar ? (st + sz + ((i - st) >> 2)) : i;
  val[9] = haspar;

  const int dcol = h * 64 + g * 16;
  const ushort_t* qp = Q + (size_t)row * DM + dcol;
  s16x8 q0 = *reinterpret_cast<const s16x8*>(qp);
  s16x8 q1 = *reinterpret_cast<const s16x8*>(qp + 8);
  float qf[16];
  #pragma unroll
  for (int j = 0; j < 8; j++){ qf[j] = b2f((ushort_t)q0[j]); qf[8 + j] = b2f((ushort_t)q1[j]); }

  size_t koff[10];
  float sc[10];
  #pragma unroll
  for (int s = 0; s < 10; s++){
    koff[s] = (size_t)(brow0 + key[s]) * 2048 + dcol;
    const ushort_t* kp = KV + koff[s];
    s16x8 k0 = *reinterpret_cast<const s16x8*>(kp);
    s16x8 k1 = *reinterpret_cast<const s16x8*>(kp + 8);
    float p = 0.f;
    #pragma unroll
    for (int j = 0; j < 8; j++){
      p += qf[j]     * b2f((ushort_t)k0[j]);
      p += qf[8 + j] * b2f((ushort_t)k1[j]);
    }
    p += __shfl_xor(p, 16);
    p += __shfl_xor(p, 32);
    sc[s] = val[s] ? p : -1e30f;
  }

  float m = sc[0];
  #pragma unroll
  for (int s = 1; s < 10; s++) m = fmaxf(m, sc[s]);
  float e[10]; float sum = 0.f;
  #pragma unroll
  for (int s = 0; s < 10; s++){ e[s] = __expf(sc[s] - m); sum += e[s]; }
  const float inv = 1.0f / sum;

  float accv[16];
  #pragma unroll
  for (int j = 0; j < 16; j++) accv[j] = 0.f;
  #pragma unroll
  for (int s = 0; s < 10; s++){
    const ushort_t* vp = KV + koff[s] + 1024;
    s16x8 v0 = *reinterpret_cast<const s16x8*>(vp);
    s16x8 v1 = *reinterpret_cast<const s16x8*>(vp + 8);
    const float w = e[s];
    #pragma unroll
    for (int j = 0; j < 8; j++){
      accv[j]     += w * b2f((ushort_t)v0[j]);
      accv[8 + j] += w * b2f((ushort_t)v1[j]);
    }
  }

  // sigma store: lane covers quads j = 4*(g&1)+m of 32-block (2h + (g>>1));
  // quad m -> short offset 8*m + 4*(g&1) within the block.
  ushort_t* op = ctx + (size_t)row * DM + 32 * (2 * h + (g >> 1)) + 4 * (g & 1);
  #pragma unroll
  for (int m2 = 0; m2 < 4; m2++){
    uint2 o;
    o.x = cvtpk(accv[4*m2+0]*inv, accv[4*m2+1]*inv);
    o.y = cvtpk(accv[4*m2+2]*inv, accv[4*m2+3]*inv);
    *reinterpret_cast<uint2*>(op + 8 * m2) = o;
  }
}

// ---------------------------------------------------------------- launch
extern "C" void kernel_launch(void* const* d_in, const int* in_sizes, int n_in,
                              void* d_out, int out_size, void* d_ws, size_t ws_size,
                              hipStream_t stream){
  (void)in_sizes; (void)n_in; (void)out_size; (void)ws_size;
  const float* x     = (const float*)d_in[0];
  const float* Wq    = (const float*)d_in[1];
  const float* Wk    = (const float*)d_in[2];
  const float* Wv    = (const float*)d_in[3];
  const float* Wfc   = (const float*)d_in[4];
  const float* bfc   = (const float*)d_in[5];
  const float* gamma = (const float*)d_in[6];
  const float* beta  = (const float*)d_in[7];
  float* out = (float*)d_out;

  char* ws = (char*)d_ws;
  const size_t SLAB = (size_t)BROWS * DM * sizeof(ushort_t);   // 11,141,120 B
  // C [0, SLAB): weights (sigma) + vectors
  ushort_t* Wqkv_t = (ushort_t*)(ws);                           // 6 MB
  ushort_t* Wfc_t  = (ushort_t*)(ws + 6291456);                 // 2 MB
  float*    cg     = (float*)(ws + 8388608);
  float*    cb     = (float*)(ws + 8392704);
  float*    muv    = (float*)(ws + 8396800);
  float*    rsv    = (float*)(ws + 8418560);
  // D [SLAB, 2*SLAB): Q -> ctx (in place, ctx in sigma layout)
  ushort_t* Qb  = (ushort_t*)(ws + SLAB);
  ushort_t* ctx = Qb;
  // E [2*SLAB, 4*SLAB): KV interleaved [row][K|V] stride 2048
  ushort_t* KVb = (ushort_t*)(ws + 2 * SLAB);
  // G [4*SLAB, 5*SLAB): x as bf16, sigma layout
  ushort_t* x_bf = (ushort_t*)(ws + 4 * SLAB);

  stats_kernel<<<BROWS, 256, 0, stream>>>(x, muv, rsv, x_bf);
  cvec_kernel<<<64, 256, 0, stream>>>(Wq, gamma, beta, cg, cb);
  trans_kernel<<<dim3(16, 16, 4), 256, 0, stream>>>(Wq, Wk, Wv, Wfc, gamma, Wqkv_t, Wfc_t);
  qkv_gemm<<<1032, 256, 0, stream>>>(x_bf, Wqkv_t, Qb, KVb, cg, cb, muv, rsv);
  attn_kernel<<<L_TOT, 256, 0, stream>>>(Qb, KVb, ctx);
  fc_gemm<<<680, 256, 0, stream>>>(ctx, Wfc_t, bfc, x, out);
}